// Round 1
// baseline (723.297 us; speedup 1.0000x reference)
//
#include <hip/hip_runtime.h>
#include <math.h>

#define HDIM  512
#define NHEAD 8
#define HEADD 64
#define BATCH 4
#define SEQ   1024
#define RELN  2048

__device__ __forceinline__ float dot4f(float4 a, float4 b, float acc) {
    acc = fmaf(a.x, b.x, acc);
    acc = fmaf(a.y, b.y, acc);
    acc = fmaf(a.z, b.z, acc);
    acc = fmaf(a.w, b.w, acc);
    return acc;
}

// ---------------- rel = emb(2048,512) @ w_r_w(512,64) + w_r_b ----------------
// grid: 2048 blocks x 64 threads. Block l computes rel[l][0..63].
__global__ void rel_kernel(const float* __restrict__ w_r_w,
                           const float* __restrict__ w_r_b,
                           float* __restrict__ rel)
{
    __shared__ float emb_s[HDIM];
    const int l = blockIdx.x;
    const int d = threadIdx.x;
    const float pos  = (float)(l - SEQ);               // pos = arange(-L, L)
    const float coef = (float)(-9.210340371976184 / 255.0);  // -ln(10000)/(half-1)
    #pragma unroll
    for (int u = 0; u < 8; ++u) {
        int h  = u * 64 + d;
        int hh = (h < 256) ? h : (h - 256);
        float fr  = expf((float)hh * coef);
        float ang = pos * fr;
        emb_s[h] = (h < 256) ? sinf(ang) : cosf(ang);
    }
    __syncthreads();
    float acc = w_r_b[d];
    for (int h = 0; h < HDIM; ++h) {
        acc = fmaf(emb_s[h], w_r_w[h * HEADD + d], acc);
    }
    rel[(size_t)l * HEADD + d] = acc;
}

// ---------------- C(4096x512) = A(4096x512) @ W(512x512) + bias ----------------
// 64x64 tile, 256 threads, 4x4 microtile, K-step 16.
__global__ __launch_bounds__(256) void proj_kernel(
    const float* __restrict__ A, const float* __restrict__ W,
    const float* __restrict__ bias, float* __restrict__ C)
{
    __shared__ float As[16][68];   // [k][m], padded
    __shared__ float Bs[16][64];   // [k][n]
    const int t  = threadIdx.x;
    const int m0 = blockIdx.y * 64;
    const int n0 = blockIdx.x * 64;
    const int tx = t & 15, ty = t >> 4;
    float acc[4][4] = {};
    for (int k0 = 0; k0 < HDIM; k0 += 16) {
        {
            int row = t >> 2, kq = (t & 3) * 4;
            float4 a4 = *(const float4*)(A + (size_t)(m0 + row) * HDIM + k0 + kq);
            As[kq + 0][row] = a4.x;
            As[kq + 1][row] = a4.y;
            As[kq + 2][row] = a4.z;
            As[kq + 3][row] = a4.w;
        }
        {
            int kk = t >> 4, nq = (t & 15) * 4;
            *(float4*)&Bs[kk][nq] = *(const float4*)(W + (size_t)(k0 + kk) * HDIM + n0 + nq);
        }
        __syncthreads();
        #pragma unroll
        for (int kk = 0; kk < 16; ++kk) {
            float4 a4 = *(const float4*)&As[kk][ty * 4];
            float4 b4 = *(const float4*)&Bs[kk][tx * 4];
            float av[4] = {a4.x, a4.y, a4.z, a4.w};
            float bv[4] = {b4.x, b4.y, b4.z, b4.w};
            #pragma unroll
            for (int mm = 0; mm < 4; ++mm)
                #pragma unroll
                for (int nn = 0; nn < 4; ++nn)
                    acc[mm][nn] = fmaf(av[mm], bv[nn], acc[mm][nn]);
        }
        __syncthreads();
    }
    #pragma unroll
    for (int mm = 0; mm < 4; ++mm) {
        int r = m0 + ty * 4 + mm;
        int cc = n0 + tx * 4;
        float4 o;
        o.x = acc[mm][0] + bias[cc + 0];
        o.y = acc[mm][1] + bias[cc + 1];
        o.z = acc[mm][2] + bias[cc + 2];
        o.w = acc[mm][3] + bias[cc + 3];
        *(float4*)(C + (size_t)r * HDIM + cc) = o;
    }
}

// ---------------- fused flash attention with relative-position terms ----------------
// grid: (L/32, NH, B), 256 threads. thread = (il 0..31, c 0..7); c owns d-slice c*8..c*8+7.
__global__ __launch_bounds__(256) void flash_kernel(
    const float* __restrict__ key,   // (B, L, H) raw
    const float* __restrict__ qws,   // (B, L, H) projected q
    const float* __restrict__ vws,   // (B, L, H) projected v
    const float* __restrict__ rel,   // (2048, 64)
    const float* __restrict__ rrb,   // (NH*HD)
    const float* __restrict__ rwb,   // (NH*HD)
    const int*   __restrict__ seqp,
    float* __restrict__ out)         // (B, L, H)
{
    __shared__ float k_s[32][68];
    __shared__ float v_s[32][68];
    __shared__ float r2_s[63][68];
    __shared__ float r3_s[63][68];

    const int i0 = blockIdx.x * 32;
    const int n  = blockIdx.y;
    const int b  = blockIdx.z;
    const int t  = threadIdx.x;
    const int il = t >> 3;
    const int c  = t & 7;
    const int S  = seqp[0];

    // q (+ r_r_bias) and (+ r_w_bias) in registers
    const float* qp = qws + ((size_t)b * SEQ + i0 + il) * HDIM + n * HEADD + c * 8;
    float4 q0 = *(const float4*)qp;
    float4 q1 = *(const float4*)(qp + 4);
    float4 ra0 = *(const float4*)(rrb + n * HEADD + c * 8);
    float4 ra1 = *(const float4*)(rrb + n * HEADD + c * 8 + 4);
    float4 rb0 = *(const float4*)(rwb + n * HEADD + c * 8);
    float4 rb1 = *(const float4*)(rwb + n * HEADD + c * 8 + 4);
    float4 qa0 = make_float4(q0.x + ra0.x, q0.y + ra0.y, q0.z + ra0.z, q0.w + ra0.w);
    float4 qa1 = make_float4(q1.x + ra1.x, q1.y + ra1.y, q1.z + ra1.z, q1.w + ra1.w);
    float4 qb0 = make_float4(q0.x + rb0.x, q0.y + rb0.y, q0.z + rb0.z, q0.w + rb0.w);
    float4 qb1 = make_float4(q1.x + rb1.x, q1.y + rb1.y, q1.z + rb1.z, q1.w + rb1.w);

    float m = -1e30f, lsum = 0.0f;
    float acc[8] = {0, 0, 0, 0, 0, 0, 0, 0};

    for (int j0 = 0; j0 < S; j0 += 32) {
        // stage K (raw key) and V rows for this chunk
        const float* kp = key + ((size_t)b * SEQ + j0 + il) * HDIM + n * HEADD + c * 8;
        *(float4*)&k_s[il][c * 8]     = *(const float4*)kp;
        *(float4*)&k_s[il][c * 8 + 4] = *(const float4*)(kp + 4);
        const float* vp = vws + ((size_t)b * SEQ + j0 + il) * HDIM + n * HEADD + c * 8;
        *(float4*)&v_s[il][c * 8]     = *(const float4*)vp;
        *(float4*)&v_s[il][c * 8 + 4] = *(const float4*)(vp + 4);
        // stage the two 63-row rel bands:
        // term2: l = L + j - i in [base2, base2+62]; term3: m = L + i - j in [base3, base3+62]
        const int base2 = SEQ + j0 - i0 - 31;
        const int base3 = SEQ + i0 - j0 - 31;
        for (int u = t; u < 63 * 16; u += 256) {
            int row = u >> 4, c4 = (u & 15) << 2;
            *(float4*)&r2_s[row][c4] = *(const float4*)(rel + (size_t)(base2 + row) * HEADD + c4);
            *(float4*)&r3_s[row][c4] = *(const float4*)(rel + (size_t)(base3 + row) * HEADD + c4);
        }
        __syncthreads();

        float sreg[32];
        #pragma unroll
        for (int jl = 0; jl < 32; ++jl) {
            float4 k0 = *(const float4*)&k_s[jl][c * 8];
            float4 k1 = *(const float4*)&k_s[jl][c * 8 + 4];
            int i2 = jl - il + 31;
            int i3 = il - jl + 31;
            float4 r20 = *(const float4*)&r2_s[i2][c * 8];
            float4 r21 = *(const float4*)&r2_s[i2][c * 8 + 4];
            float4 r30 = *(const float4*)&r3_s[i3][c * 8];
            float4 r31 = *(const float4*)&r3_s[i3][c * 8 + 4];
            float s1 = dot4f(qa1, k1, dot4f(qa0, k0, 0.0f));
            float s2 = dot4f(qb1, r21, dot4f(qb0, r20, 0.0f));
            float s3 = dot4f(k1, r31, dot4f(k0, r30, 0.0f));
            float p = s1 + s2 + s3;
            p += __shfl_xor(p, 1, 64);
            p += __shfl_xor(p, 2, 64);
            p += __shfl_xor(p, 4, 64);
            sreg[jl] = ((j0 + jl) < S) ? p : -1e30f;
        }

        // online softmax update (each lane holds the full 32-wide chunk for its row)
        float mloc = sreg[0];
        #pragma unroll
        for (int jl = 1; jl < 32; ++jl) mloc = fmaxf(mloc, sreg[jl]);
        float mnew = fmaxf(m, mloc);
        float sc = __expf(m - mnew);
        lsum *= sc;
        #pragma unroll
        for (int d = 0; d < 8; ++d) acc[d] *= sc;
        #pragma unroll
        for (int jl = 0; jl < 32; ++jl) {
            float p = __expf(sreg[jl] - mnew);
            lsum += p;
            float4 v0 = *(const float4*)&v_s[jl][c * 8];
            float4 v1 = *(const float4*)&v_s[jl][c * 8 + 4];
            acc[0] = fmaf(p, v0.x, acc[0]);
            acc[1] = fmaf(p, v0.y, acc[1]);
            acc[2] = fmaf(p, v0.z, acc[2]);
            acc[3] = fmaf(p, v0.w, acc[3]);
            acc[4] = fmaf(p, v1.x, acc[4]);
            acc[5] = fmaf(p, v1.y, acc[5]);
            acc[6] = fmaf(p, v1.z, acc[6]);
            acc[7] = fmaf(p, v1.w, acc[7]);
        }
        m = mnew;
        __syncthreads();
    }

    float inv = 1.0f / lsum;
    float* op = out + ((size_t)b * SEQ + i0 + il) * HDIM + n * HEADD + c * 8;
    float4 o0 = make_float4(acc[0] * inv, acc[1] * inv, acc[2] * inv, acc[3] * inv);
    float4 o1 = make_float4(acc[4] * inv, acc[5] * inv, acc[6] * inv, acc[7] * inv);
    *(float4*)op = o0;
    *(float4*)(op + 4) = o1;
}

extern "C" void kernel_launch(void* const* d_in, const int* in_sizes, int n_in,
                              void* d_out, int out_size, void* d_ws, size_t ws_size,
                              hipStream_t stream) {
    (void)in_sizes; (void)n_in; (void)out_size; (void)ws_size;
    const float* query = (const float*)d_in[0];
    const float* key   = (const float*)d_in[1];
    const float* value = (const float*)d_in[2];
    const float* w_q_w = (const float*)d_in[3];
    const float* w_q_b = (const float*)d_in[4];
    const float* w_v_w = (const float*)d_in[5];
    const float* w_v_b = (const float*)d_in[6];
    const float* w_r_w = (const float*)d_in[7];
    const float* w_r_b = (const float*)d_in[8];
    const float* rrb   = (const float*)d_in[9];
    const float* rwb   = (const float*)d_in[10];
    const int*   seqp  = (const int*)d_in[11];
    float* out = (float*)d_out;

    float* ws  = (float*)d_ws;
    float* rel = ws;                               // 2048*64
    float* qws = rel + (size_t)RELN * HEADD;       // 4096*512
    float* vws = qws + (size_t)BATCH * SEQ * HDIM; // 4096*512

    hipLaunchKernelGGL(rel_kernel, dim3(RELN), dim3(64), 0, stream, w_r_w, w_r_b, rel);
    hipLaunchKernelGGL(proj_kernel, dim3(8, 64), dim3(256), 0, stream, query, w_q_w, w_q_b, qws);
    hipLaunchKernelGGL(proj_kernel, dim3(8, 64), dim3(256), 0, stream, value, w_v_w, w_v_b, vws);
    hipLaunchKernelGGL(flash_kernel, dim3(SEQ / 32, NHEAD, BATCH), dim3(256), 0, stream,
                       key, qws, vws, rel, rrb, rwb, seqp, out);
}

// Round 2
// 301.372 us; speedup vs baseline: 2.4000x; 2.4000x over previous
//
#include <hip/hip_runtime.h>
#include <math.h>

#define HDIM  512
#define NHEAD 8
#define HEADD 64
#define BATCH 4
#define SEQ   1024
#define RELN  2048

typedef __attribute__((ext_vector_type(8))) short s16x8;
typedef __attribute__((ext_vector_type(4))) float f32x4;

__device__ __forceinline__ unsigned short f2bf(float x) {
    unsigned u = __float_as_uint(x);
    u += 0x7fffu + ((u >> 16) & 1u);
    return (unsigned short)(u >> 16);
}

// ---------------- rel = emb(2048,512) @ w_r_w(512,64) + w_r_b -> bf16 ----------------
__global__ void rel_kernel(const float* __restrict__ w_r_w,
                           const float* __restrict__ w_r_b,
                           unsigned short* __restrict__ relbf)
{
    __shared__ float emb_s[HDIM];
    const int l = blockIdx.x;
    const int d = threadIdx.x;
    const float pos  = (float)(l - SEQ);
    const float coef = (float)(-9.210340371976184 / 255.0);  // -ln(10000)/(half-1)
    #pragma unroll
    for (int u = 0; u < 8; ++u) {
        int h  = u * 64 + d;
        int hh = (h < 256) ? h : (h - 256);
        float fr  = expf((float)hh * coef);
        float ang = pos * fr;
        emb_s[h] = (h < 256) ? sinf(ang) : cosf(ang);
    }
    __syncthreads();
    float acc = w_r_b[d];
    for (int h = 0; h < HDIM; ++h)
        acc = fmaf(emb_s[h], w_r_w[h * HEADD + d], acc);
    relbf[(size_t)l * HEADD + d] = f2bf(acc);
}

// ---------------- f32 -> bf16 copy (for raw key) ----------------
__global__ void conv_bf16(const float* __restrict__ in, unsigned short* __restrict__ out, int n)
{
    int i = (blockIdx.x * 256 + threadIdx.x) * 4;
    if (i < n) {
        float4 v = *(const float4*)(in + i);
        ushort4 o;
        o.x = f2bf(v.x); o.y = f2bf(v.y); o.z = f2bf(v.z); o.w = f2bf(v.w);
        *(ushort4*)(out + i) = o;
    }
}

// ---------------- C = A(4096x512) @ W(512x512) + bias (+extra) -> bf16 outputs ----------------
__global__ __launch_bounds__(256) void proj_kernel(
    const float* __restrict__ A, const float* __restrict__ W,
    const float* __restrict__ bias,
    const float* __restrict__ extra1, const float* __restrict__ extra2,
    unsigned short* __restrict__ o1, unsigned short* __restrict__ o2)
{
    __shared__ float As[16][68];
    __shared__ float Bs[16][64];
    const int t  = threadIdx.x;
    const int m0 = blockIdx.y * 64;
    const int n0 = blockIdx.x * 64;
    const int tx = t & 15, ty = t >> 4;
    float acc[4][4] = {};
    for (int k0 = 0; k0 < HDIM; k0 += 16) {
        {
            int row = t >> 2, kq = (t & 3) * 4;
            float4 a4 = *(const float4*)(A + (size_t)(m0 + row) * HDIM + k0 + kq);
            As[kq + 0][row] = a4.x;
            As[kq + 1][row] = a4.y;
            As[kq + 2][row] = a4.z;
            As[kq + 3][row] = a4.w;
        }
        {
            int kk = t >> 4, nq = (t & 15) * 4;
            *(float4*)&Bs[kk][nq] = *(const float4*)(W + (size_t)(k0 + kk) * HDIM + n0 + nq);
        }
        __syncthreads();
        #pragma unroll
        for (int kk = 0; kk < 16; ++kk) {
            float4 a4 = *(const float4*)&As[kk][ty * 4];
            float4 b4 = *(const float4*)&Bs[kk][tx * 4];
            float av[4] = {a4.x, a4.y, a4.z, a4.w};
            float bv[4] = {b4.x, b4.y, b4.z, b4.w};
            #pragma unroll
            for (int mm = 0; mm < 4; ++mm)
                #pragma unroll
                for (int nn = 0; nn < 4; ++nn)
                    acc[mm][nn] = fmaf(av[mm], bv[nn], acc[mm][nn]);
        }
        __syncthreads();
    }
    #pragma unroll
    for (int mm = 0; mm < 4; ++mm) {
        int r  = m0 + ty * 4 + mm;
        int cc = n0 + tx * 4;
        float base[4];
        #pragma unroll
        for (int nn = 0; nn < 4; ++nn) base[nn] = acc[mm][nn] + bias[cc + nn];
        ushort4 pa;
        if (extra1) {
            pa.x = f2bf(base[0] + extra1[cc + 0]);
            pa.y = f2bf(base[1] + extra1[cc + 1]);
            pa.z = f2bf(base[2] + extra1[cc + 2]);
            pa.w = f2bf(base[3] + extra1[cc + 3]);
        } else {
            pa.x = f2bf(base[0]); pa.y = f2bf(base[1]);
            pa.z = f2bf(base[2]); pa.w = f2bf(base[3]);
        }
        *(ushort4*)(o1 + (size_t)r * HDIM + cc) = pa;
        if (o2) {
            ushort4 pb;
            pb.x = f2bf(base[0] + extra2[cc + 0]);
            pb.y = f2bf(base[1] + extra2[cc + 1]);
            pb.z = f2bf(base[2] + extra2[cc + 2]);
            pb.w = f2bf(base[3] + extra2[cc + 3]);
            *(ushort4*)(o2 + (size_t)r * HDIM + cc) = pb;
        }
    }
}

// ---------------- fused MFMA flash attention with relative-position terms ----------------
// grid (32, NH, B), 256 threads = 4 waves. Per 32x32 j-tile:
//   AC = Qa @ K^T ; M2 = Qb @ R2^T ; M3 = K @ R3^T   (MFMA 16x16x32 bf16)
//   S[i][j] = AC[i][j] + M2[i][j-i+31] + M3[j][i-j+31]  (LDS gather)
//   online softmax -> P bf16 -> O += P @ V (MFMA)
__global__ __launch_bounds__(256) void flash_mfma(
    const unsigned short* __restrict__ kbf,
    const unsigned short* __restrict__ qabf,
    const unsigned short* __restrict__ qbbf,
    const unsigned short* __restrict__ vbf,
    const unsigned short* __restrict__ relbf,
    const int* __restrict__ seqp,
    float* __restrict__ out)
{
    __shared__ unsigned short K_s[32][72];    // stride 36 words (==4 mod 32, balanced b128)
    __shared__ unsigned short Vt_s[64][40];   // V transposed, stride 20 words
    __shared__ unsigned short R2_s[64][72];   // rows 0..62 valid
    __shared__ unsigned short R3_s[64][72];
    __shared__ float AC_s[32][36];
    __shared__ float M2_s[32][68];
    __shared__ float M3_s[32][68];
    __shared__ unsigned short P_s[32][32];
    __shared__ float scale_s[32];
    __shared__ float lsum_s[32];

    const int t  = threadIdx.x;
    const int w  = t >> 6;
    const int l  = t & 63;
    const int i0 = blockIdx.x * 32;
    const int n  = blockIdx.y;
    const int b  = blockIdx.z;
    const int S  = seqp[0];

    const int mi   = w >> 1;      // wave's row-tile (0/1)
    const int nq   = w & 1;       // wave's col-slot
    const int colA = l & 15;
    const int g    = l >> 4;
    const int kg8  = g * 8;

    // persistent Q fragments (A-frag: row = lane&15, k = (lane>>4)*8 + 0..7)
    const int rq = i0 + mi * 16 + colA;
    const s16x8* qaP = (const s16x8*)(qabf + ((b * SEQ + rq) * HDIM + n * HEADD));
    const s16x8* qbP = (const s16x8*)(qbbf + ((b * SEQ + rq) * HDIM + n * HEADD));
    const s16x8 qa0 = qaP[g], qa1 = qaP[g + 4];
    const s16x8 qb0 = qbP[g], qb1 = qbP[g + 4];

    // softmax thread mapping: row = t>>3, 4 cols at (t&7)*4
    const int srow = t >> 3;
    const int sc8  = t & 7;

    float m_run = -1e30f, l_run = 0.0f;
    f32x4 o0 = {0.f, 0.f, 0.f, 0.f}, o1 = {0.f, 0.f, 0.f, 0.f};

    const int str  = t >> 3;
    const int std8 = (t & 7) * 8;

    for (int j0 = 0; j0 < S; j0 += 32) {
        // ---------- stage K, V^T, rel bands ----------
        {
            int gidx = (b * SEQ + j0 + str) * HDIM + n * HEADD + std8;
            *(uint4*)&K_s[str][std8] = *(const uint4*)(kbf + gidx);
            union { uint4 q; unsigned short s[8]; } vv;
            vv.q = *(const uint4*)(vbf + gidx);
            #pragma unroll
            for (int u = 0; u < 8; ++u) Vt_s[std8 + u][str] = vv.s[u];
        }
        {
            int base2 = SEQ + j0 - i0 - 31;   // rel row for u2=0
            int base3 = SEQ + i0 - j0 - 31;
            for (int u = t; u < 63 * 8; u += 256) {
                int rr = u >> 3, dd = (u & 7) * 8;
                *(uint4*)&R2_s[rr][dd] = *(const uint4*)(relbf + (base2 + rr) * HEADD + dd);
                *(uint4*)&R3_s[rr][dd] = *(const uint4*)(relbf + (base3 + rr) * HEADD + dd);
            }
        }
        __syncthreads();

        // ---------- score MFMAs ----------
        {
            // AC tile (mi, nq): B-frag = K rows as columns (contiguous k=d)
            f32x4 cAC = {0.f, 0.f, 0.f, 0.f};
            {
                int jb = nq * 16 + colA;
                s16x8 kb0 = *(const s16x8*)&K_s[jb][kg8];
                s16x8 kb1 = *(const s16x8*)&K_s[jb][kg8 + 32];
                cAC = __builtin_amdgcn_mfma_f32_16x16x32_bf16(qa0, kb0, cAC, 0, 0, 0);
                cAC = __builtin_amdgcn_mfma_f32_16x16x32_bf16(qa1, kb1, cAC, 0, 0, 0);
            }
            #pragma unroll
            for (int rr = 0; rr < 4; ++rr)
                AC_s[mi * 16 + g * 4 + rr][nq * 16 + colA] = cAC[rr];

            // M2 tiles (mi, ni), ni = 2*nq + {0,1}
            #pragma unroll
            for (int half = 0; half < 2; ++half) {
                int ni = nq * 2 + half;
                int u  = ni * 16 + colA;
                f32x4 c2 = {0.f, 0.f, 0.f, 0.f};
                s16x8 rb0 = *(const s16x8*)&R2_s[u][kg8];
                s16x8 rb1 = *(const s16x8*)&R2_s[u][kg8 + 32];
                c2 = __builtin_amdgcn_mfma_f32_16x16x32_bf16(qb0, rb0, c2, 0, 0, 0);
                c2 = __builtin_amdgcn_mfma_f32_16x16x32_bf16(qb1, rb1, c2, 0, 0, 0);
                #pragma unroll
                for (int rr = 0; rr < 4; ++rr)
                    M2_s[mi * 16 + g * 4 + rr][ni * 16 + colA] = c2[rr];
            }

            // M3 tiles (rows = K rows of tile mi): A-frag from K_s
            s16x8 ka0 = *(const s16x8*)&K_s[mi * 16 + colA][kg8];
            s16x8 ka1 = *(const s16x8*)&K_s[mi * 16 + colA][kg8 + 32];
            #pragma unroll
            for (int half = 0; half < 2; ++half) {
                int ni = nq * 2 + half;
                int u  = ni * 16 + colA;
                f32x4 c3 = {0.f, 0.f, 0.f, 0.f};
                s16x8 rb0 = *(const s16x8*)&R3_s[u][kg8];
                s16x8 rb1 = *(const s16x8*)&R3_s[u][kg8 + 32];
                c3 = __builtin_amdgcn_mfma_f32_16x16x32_bf16(ka0, rb0, c3, 0, 0, 0);
                c3 = __builtin_amdgcn_mfma_f32_16x16x32_bf16(ka1, rb1, c3, 0, 0, 0);
                #pragma unroll
                for (int rr = 0; rr < 4; ++rr)
                    M3_s[mi * 16 + g * 4 + rr][ni * 16 + colA] = c3[rr];
            }
        }
        __syncthreads();

        // ---------- online softmax ----------
        {
            f32x4 ac = *(const f32x4*)&AC_s[srow][sc8 * 4];
            float sv[4];
            #pragma unroll
            for (int u = 0; u < 4; ++u) {
                int col = sc8 * 4 + u;
                float s2 = M2_s[srow][col - srow + 31];
                float s3 = M3_s[col][srow - col + 31];
                float s  = ac[u] + s2 + s3;
                sv[u] = ((j0 + col) < S) ? s : -1e30f;
            }
            float mloc = fmaxf(fmaxf(sv[0], sv[1]), fmaxf(sv[2], sv[3]));
            #pragma unroll
            for (int off = 1; off < 8; off <<= 1)
                mloc = fmaxf(mloc, __shfl_xor(mloc, off));
            float mnew = fmaxf(m_run, mloc);
            float sc = exp2f((m_run - mnew) * 1.4426950408889634f);
            float p[4], ps;
            #pragma unroll
            for (int u = 0; u < 4; ++u)
                p[u] = exp2f((sv[u] - mnew) * 1.4426950408889634f);
            ps = p[0] + p[1] + p[2] + p[3];
            #pragma unroll
            for (int off = 1; off < 8; off <<= 1)
                ps += __shfl_xor(ps, off);
            l_run = l_run * sc + ps;
            m_run = mnew;
            ushort4 pk;
            pk.x = f2bf(p[0]); pk.y = f2bf(p[1]); pk.z = f2bf(p[2]); pk.w = f2bf(p[3]);
            *(ushort4*)&P_s[srow][sc8 * 4] = pk;
            if (sc8 == 0) scale_s[srow] = sc;
        }
        __syncthreads();

        // ---------- PV ----------
        {
            #pragma unroll
            for (int rr = 0; rr < 4; ++rr) {
                float scl = scale_s[mi * 16 + g * 4 + rr];
                o0[rr] *= scl;
                o1[rr] *= scl;
            }
            s16x8 pa  = *(const s16x8*)&P_s[mi * 16 + colA][kg8];
            s16x8 vb0 = *(const s16x8*)&Vt_s[nq * 16 + colA][kg8];
            s16x8 vb1 = *(const s16x8*)&Vt_s[nq * 16 + 32 + colA][kg8];
            o0 = __builtin_amdgcn_mfma_f32_16x16x32_bf16(pa, vb0, o0, 0, 0, 0);
            o1 = __builtin_amdgcn_mfma_f32_16x16x32_bf16(pa, vb1, o1, 0, 0, 0);
        }
        __syncthreads();
    }

    if (sc8 == 0) lsum_s[srow] = l_run;
    __syncthreads();

    #pragma unroll
    for (int rr = 0; rr < 4; ++rr) {
        int row = mi * 16 + g * 4 + rr;
        float inv = 1.0f / lsum_s[row];
        int obase = (b * SEQ + i0 + row) * HDIM + n * HEADD;
        out[obase + nq * 16 + colA]      = o0[rr] * inv;
        out[obase + nq * 16 + 32 + colA] = o1[rr] * inv;
    }
}

extern "C" void kernel_launch(void* const* d_in, const int* in_sizes, int n_in,
                              void* d_out, int out_size, void* d_ws, size_t ws_size,
                              hipStream_t stream) {
    (void)in_sizes; (void)n_in; (void)out_size; (void)ws_size;
    const float* query = (const float*)d_in[0];
    const float* key   = (const float*)d_in[1];
    const float* value = (const float*)d_in[2];
    const float* w_q_w = (const float*)d_in[3];
    const float* w_q_b = (const float*)d_in[4];
    const float* w_v_w = (const float*)d_in[5];
    const float* w_v_b = (const float*)d_in[6];
    const float* w_r_w = (const float*)d_in[7];
    const float* w_r_b = (const float*)d_in[8];
    const float* rrb   = (const float*)d_in[9];
    const float* rwb   = (const float*)d_in[10];
    const int*   seqp  = (const int*)d_in[11];
    float* out = (float*)d_out;

    unsigned short* wsp   = (unsigned short*)d_ws;
    unsigned short* relbf = wsp;                                   // 2048*64
    unsigned short* kbf   = relbf + (size_t)RELN * HEADD;          // 4096*512
    unsigned short* qabf  = kbf  + (size_t)BATCH * SEQ * HDIM;
    unsigned short* qbbf  = qabf + (size_t)BATCH * SEQ * HDIM;
    unsigned short* vbf   = qbbf + (size_t)BATCH * SEQ * HDIM;

    hipLaunchKernelGGL(rel_kernel, dim3(RELN), dim3(64), 0, stream, w_r_w, w_r_b, relbf);
    hipLaunchKernelGGL(conv_bf16, dim3(2048), dim3(256), 0, stream,
                       key, kbf, BATCH * SEQ * HDIM);
    hipLaunchKernelGGL(proj_kernel, dim3(8, 64), dim3(256), 0, stream,
                       query, w_q_w, w_q_b, rrb, rwb, qabf, qbbf);
    hipLaunchKernelGGL(proj_kernel, dim3(8, 64), dim3(256), 0, stream,
                       value, w_v_w, w_v_b, (const float*)nullptr, (const float*)nullptr,
                       vbf, (unsigned short*)nullptr);
    hipLaunchKernelGGL(flash_mfma, dim3(SEQ / 32, NHEAD, BATCH), dim3(256), 0, stream,
                       kbf, qabf, qbbf, vbf, relbf, seqp, out);
}

// Round 3
// 252.913 us; speedup vs baseline: 2.8599x; 1.1916x over previous
//
#include <hip/hip_runtime.h>
#include <math.h>

#define HDIM  512
#define NHEAD 8
#define HEADD 64
#define BATCH 4
#define SEQ   1024
#define RELN  2048
#define LOG2E 1.4426950408889634f

typedef __attribute__((ext_vector_type(8))) short s16x8;
typedef __attribute__((ext_vector_type(4))) float f32x4;

__device__ __forceinline__ unsigned short f2bf(float x) {
    unsigned u = __float_as_uint(x);
    u += 0x7fffu + ((u >> 16) & 1u);
    return (unsigned short)(u >> 16);
}
__device__ __forceinline__ float bf2f(unsigned short h) {
    return __uint_as_float(((unsigned)h) << 16);
}

// ---------------- rel = emb(2048,512) @ w_r_w(512,64) + w_r_b -> bf16 ----------------
// grid 2048 x 256 threads; k-split over 4 chunks of 128.
__global__ __launch_bounds__(256) void rel_kernel(const float* __restrict__ w_r_w,
                                                  const float* __restrict__ w_r_b,
                                                  unsigned short* __restrict__ relbf)
{
    __shared__ float emb_s[HDIM];
    __shared__ float part[4][64];
    const int l = blockIdx.x;
    const int t = threadIdx.x;
    const float pos  = (float)(l - SEQ);
    const float coef = (float)(-9.210340371976184 / 255.0);  // -ln(10000)/(half-1)
    {
        float fr  = expf((float)t * coef);
        float ang = pos * fr;
        emb_s[t]       = sinf(ang);
        emb_s[t + 256] = cosf(ang);
    }
    __syncthreads();
    const int d  = t & 63;
    const int ks = t >> 6;
    const float* wp = w_r_w + d;
    const int h0 = ks * 128;
    float a0 = 0.f, a1 = 0.f, a2 = 0.f, a3 = 0.f;
    #pragma unroll 8
    for (int h = 0; h < 128; h += 4) {
        a0 = fmaf(emb_s[h0 + h + 0], wp[(size_t)(h0 + h + 0) * HEADD], a0);
        a1 = fmaf(emb_s[h0 + h + 1], wp[(size_t)(h0 + h + 1) * HEADD], a1);
        a2 = fmaf(emb_s[h0 + h + 2], wp[(size_t)(h0 + h + 2) * HEADD], a2);
        a3 = fmaf(emb_s[h0 + h + 3], wp[(size_t)(h0 + h + 3) * HEADD], a3);
    }
    part[ks][d] = (a0 + a1) + (a2 + a3);
    __syncthreads();
    if (ks == 0) {
        float acc = part[0][d] + part[1][d] + part[2][d] + part[3][d] + w_r_b[d];
        relbf[(size_t)l * HEADD + d] = f2bf(acc);
    }
}

// ---------------- W (512x512 f32) -> transposed hi/lo bf16 [n][k] ----------------
__global__ __launch_bounds__(256) void wsplit_kernel(
    const float* __restrict__ wq, const float* __restrict__ wv,
    unsigned short* __restrict__ wtq_hi, unsigned short* __restrict__ wtq_lo,
    unsigned short* __restrict__ wtv_hi, unsigned short* __restrict__ wtv_lo)
{
    __shared__ float T[64][68];
    const float* W = blockIdx.z ? wv : wq;
    unsigned short* Ohi = blockIdx.z ? wtv_hi : wtq_hi;
    unsigned short* Olo = blockIdx.z ? wtv_lo : wtq_lo;
    const int k0 = blockIdx.y * 64, n0 = blockIdx.x * 64;
    const int t = threadIdx.x;
    const int r = t >> 2, c16 = (t & 3) * 16;
    #pragma unroll
    for (int u = 0; u < 4; ++u) {
        float4 v = *(const float4*)(W + (size_t)(k0 + r) * HDIM + n0 + c16 + u * 4);
        *(float4*)&T[r][c16 + u * 4] = v;
    }
    __syncthreads();
    __align__(16) unsigned short hi[16], lo[16];
    #pragma unroll
    for (int u = 0; u < 16; ++u) {
        float x = T[c16 + u][r];
        unsigned short h = f2bf(x);
        hi[u] = h;
        lo[u] = f2bf(x - bf2f(h));
    }
    size_t base = (size_t)(n0 + r) * HDIM + k0 + c16;
    *(uint4*)(Ohi + base)     = *(uint4*)&hi[0];
    *(uint4*)(Ohi + base + 8) = *(uint4*)&hi[8];
    *(uint4*)(Olo + base)     = *(uint4*)&lo[0];
    *(uint4*)(Olo + base + 8) = *(uint4*)&lo[8];
}

// ---------------- f32 -> bf16 copy (raw key) ----------------
__global__ void conv_bf16(const float* __restrict__ in, unsigned short* __restrict__ out, int n)
{
    int i = (blockIdx.x * 256 + threadIdx.x) * 4;
    if (i < n) {
        float4 v = *(const float4*)(in + i);
        ushort4 o;
        o.x = f2bf(v.x); o.y = f2bf(v.y); o.z = f2bf(v.z); o.w = f2bf(v.w);
        *(ushort4*)(out + i) = o;
    }
}

// ---------------- split-bf16 MFMA projection: C = A(4096x512) @ W + bias ----------------
// MODE 0: two bf16 row-major outputs (C+bias+e1 -> out1, C+bias+e2 -> out2)
// MODE 1: one transposed output vT[(b,n,d)][j] = C+bias
template<int MODE>
__global__ __launch_bounds__(256) void proj_mfma(
    const float* __restrict__ A,
    const unsigned short* __restrict__ Wt_hi,
    const unsigned short* __restrict__ Wt_lo,
    const float* __restrict__ bias,
    const float* __restrict__ e1,
    const float* __restrict__ e2,
    unsigned short* __restrict__ out1,
    unsigned short* __restrict__ out2)
{
    __shared__ unsigned short Ah[64][40], Al[64][40], Bh[64][40], Bl[64][40];
    __shared__ unsigned short Ls[64][72];
    const int t = threadIdx.x;
    const int w = t >> 6, l = t & 63, colA = l & 15, g = l >> 4, kg8 = g * 8;
    const int n0 = blockIdx.x * 64, m0 = blockIdx.y * 64;
    const int mi = w >> 1, ni = w & 1;
    const int sr = t >> 2, skc = (t & 3) * 8;
    f32x4 acc[2][2] = {};

    for (int k0 = 0; k0 < HDIM; k0 += 32) {
        {
            const float* ap = A + (size_t)(m0 + sr) * HDIM + k0 + skc;
            float4 x0 = *(const float4*)ap;
            float4 x1 = *(const float4*)(ap + 4);
            float xv[8] = {x0.x, x0.y, x0.z, x0.w, x1.x, x1.y, x1.z, x1.w};
            __align__(16) unsigned short hh[8], ll[8];
            #pragma unroll
            for (int u = 0; u < 8; ++u) {
                unsigned short h = f2bf(xv[u]);
                hh[u] = h;
                ll[u] = f2bf(xv[u] - bf2f(h));
            }
            *(uint4*)&Ah[sr][skc] = *(uint4*)hh;
            *(uint4*)&Al[sr][skc] = *(uint4*)ll;
            *(uint4*)&Bh[sr][skc] = *(const uint4*)(Wt_hi + (size_t)(n0 + sr) * HDIM + k0 + skc);
            *(uint4*)&Bl[sr][skc] = *(const uint4*)(Wt_lo + (size_t)(n0 + sr) * HDIM + k0 + skc);
        }
        __syncthreads();
        s16x8 ah[2], al[2], bh[2], bl[2];
        #pragma unroll
        for (int mt = 0; mt < 2; ++mt) {
            ah[mt] = *(const s16x8*)&Ah[mi * 32 + mt * 16 + colA][kg8];
            al[mt] = *(const s16x8*)&Al[mi * 32 + mt * 16 + colA][kg8];
        }
        #pragma unroll
        for (int nt = 0; nt < 2; ++nt) {
            bh[nt] = *(const s16x8*)&Bh[ni * 32 + nt * 16 + colA][kg8];
            bl[nt] = *(const s16x8*)&Bl[ni * 32 + nt * 16 + colA][kg8];
        }
        #pragma unroll
        for (int mt = 0; mt < 2; ++mt)
            #pragma unroll
            for (int nt = 0; nt < 2; ++nt) {
                acc[mt][nt] = __builtin_amdgcn_mfma_f32_16x16x32_bf16(al[mt], bh[nt], acc[mt][nt], 0, 0, 0);
                acc[mt][nt] = __builtin_amdgcn_mfma_f32_16x16x32_bf16(ah[mt], bl[nt], acc[mt][nt], 0, 0, 0);
                acc[mt][nt] = __builtin_amdgcn_mfma_f32_16x16x32_bf16(ah[mt], bh[nt], acc[mt][nt], 0, 0, 0);
            }
        __syncthreads();
    }

    float bv[2], ev1[2], ev2[2];
    #pragma unroll
    for (int nt = 0; nt < 2; ++nt) {
        int gn = n0 + ni * 32 + nt * 16 + colA;
        bv[nt] = bias[gn];
        if (MODE == 0) { ev1[nt] = e1[gn]; ev2[nt] = e2[gn]; }
    }

    if (MODE == 0) {
        #pragma unroll
        for (int mt = 0; mt < 2; ++mt)
            #pragma unroll
            for (int nt = 0; nt < 2; ++nt)
                #pragma unroll
                for (int rr = 0; rr < 4; ++rr)
                    Ls[mi * 32 + mt * 16 + g * 4 + rr][ni * 32 + nt * 16 + colA] =
                        f2bf(acc[mt][nt][rr] + bv[nt] + ev1[nt]);
        __syncthreads();
        {
            int r = t >> 2, c = (t & 3) * 16;
            uint4 x0 = *(uint4*)&Ls[r][c];
            uint4 x1 = *(uint4*)&Ls[r][c + 8];
            *(uint4*)(out1 + (size_t)(m0 + r) * HDIM + n0 + c)     = x0;
            *(uint4*)(out1 + (size_t)(m0 + r) * HDIM + n0 + c + 8) = x1;
        }
        __syncthreads();
        #pragma unroll
        for (int mt = 0; mt < 2; ++mt)
            #pragma unroll
            for (int nt = 0; nt < 2; ++nt)
                #pragma unroll
                for (int rr = 0; rr < 4; ++rr)
                    Ls[mi * 32 + mt * 16 + g * 4 + rr][ni * 32 + nt * 16 + colA] =
                        f2bf(acc[mt][nt][rr] + bv[nt] + ev2[nt]);
        __syncthreads();
        {
            int r = t >> 2, c = (t & 3) * 16;
            uint4 x0 = *(uint4*)&Ls[r][c];
            uint4 x1 = *(uint4*)&Ls[r][c + 8];
            *(uint4*)(out2 + (size_t)(m0 + r) * HDIM + n0 + c)     = x0;
            *(uint4*)(out2 + (size_t)(m0 + r) * HDIM + n0 + c + 8) = x1;
        }
    } else {
        // transposed store: Ls[d_local][j_local]
        #pragma unroll
        for (int mt = 0; mt < 2; ++mt)
            #pragma unroll
            for (int nt = 0; nt < 2; ++nt)
                #pragma unroll
                for (int rr = 0; rr < 4; ++rr)
                    Ls[ni * 32 + nt * 16 + colA][mi * 32 + mt * 16 + g * 4 + rr] =
                        f2bf(acc[mt][nt][rr] + bv[nt]);
        __syncthreads();
        {
            int dl = t >> 2, c = (t & 3) * 16;
            int head = n0 >> 6;
            int bb = m0 >> 10, j0 = m0 & 1023;
            uint4 x0 = *(uint4*)&Ls[dl][c];
            uint4 x1 = *(uint4*)&Ls[dl][c + 8];
            size_t vbase = ((size_t)(bb * NHEAD + head) * HEADD + dl) * SEQ + j0 + c;
            *(uint4*)(out1 + vbase)     = x0;
            *(uint4*)(out1 + vbase + 8) = x1;
        }
    }
}

// ---------------- fused MFMA flash attention, wave-role split ----------------
// grid (32, NH, B), 256 threads = 4 waves.
// W0/W1: AC rows 0..15 / 16..31 (in-register C) + full within-wave softmax.
// W2/W3: M2 (Qb@R2^T) and M3 (K@R3^T) row-halves, stored transposed bf16.
// PV: all 4 waves, O tile (rows (w&1)*16, d-cols (w>>1)*32).
__global__ __launch_bounds__(256) void flash_v3(
    const unsigned short* __restrict__ kbf,
    const unsigned short* __restrict__ qabf,
    const unsigned short* __restrict__ qbbf,
    const unsigned short* __restrict__ vT,
    const unsigned short* __restrict__ relbf,
    const int* __restrict__ seqp,
    float* __restrict__ out)
{
    __shared__ unsigned short K_s[32][72];
    __shared__ unsigned short Vt_s[64][40];
    __shared__ unsigned short R2_s[64 * 64];   // XOR-swizzled linear, rows 0..62 valid
    __shared__ unsigned short R3_s[64 * 64];
    __shared__ unsigned short M2t_s[64][36];   // [u][i] transposed
    __shared__ unsigned short M3t_s[64][36];   // [u][j] transposed
    __shared__ unsigned short P_s[32][40];
    __shared__ float scale_s[32];
    __shared__ float lsum_s[32];

    const int t = threadIdx.x;
    const int w = t >> 6, l = t & 63, colA = l & 15, g = l >> 4, kg8 = g * 8;
    const int i0 = blockIdx.x * 32;
    const int n = blockIdx.y, b = blockIdx.z;
    const int S = seqp[0];

    const int qa_row = i0 + (w & 1) * 16 + colA;
    const int qb_row = i0 + (w == 3 ? 16 : 0) + colA;
    const s16x8* qaP = (const s16x8*)(qabf + ((size_t)(b * SEQ + qa_row) * HDIM + n * HEADD));
    const s16x8* qbP = (const s16x8*)(qbbf + ((size_t)(b * SEQ + qb_row) * HDIM + n * HEADD));
    const s16x8 qa0 = qaP[g], qa1 = qaP[g + 4];
    const s16x8 qb0 = qbP[g], qb1 = qbP[g + 4];

    float m_run[4] = {-1e30f, -1e30f, -1e30f, -1e30f};
    float l_run[4] = {0.f, 0.f, 0.f, 0.f};
    f32x4 o0 = {0.f, 0.f, 0.f, 0.f}, o1 = {0.f, 0.f, 0.f, 0.f};

    const int krow = t >> 3, kc8 = (t & 7) * 8;   // K staging 32x64
    const int vrow = t >> 2, vc8 = (t & 3) * 8;   // Vt staging 64x32
    const int orow = (w & 1) * 16;                // O row offset
    const int od   = (w >> 1) * 32;               // O d offset

    for (int j0 = 0; j0 < S; j0 += 32) {
        // ---- stage K, Vt, rel bands ----
        *(uint4*)&K_s[krow][kc8] =
            *(const uint4*)(kbf + ((size_t)(b * SEQ + j0 + krow) * HDIM + n * HEADD + kc8));
        *(uint4*)&Vt_s[vrow][vc8] =
            *(const uint4*)(vT + ((size_t)((b * NHEAD + n) * HEADD + vrow) * SEQ + j0 + vc8));
        {
            const int base2 = SEQ + j0 - i0 - 31;
            const int base3 = SEQ + i0 - j0 - 31;
            #pragma unroll
            for (int rep = 0; rep < 2; ++rep) {
                int idx = t + rep * 256;
                if (idx < 63 * 8) {
                    int rw = idx >> 3, cc = (idx & 7) * 8;
                    unsigned swz = ((unsigned)(rw * 128 + cc * 2)) ^ (unsigned)((rw & 7) << 4);
                    *(uint4*)((char*)R2_s + swz) =
                        *(const uint4*)(relbf + (size_t)(base2 + rw) * HEADD + cc);
                    *(uint4*)((char*)R3_s + swz) =
                        *(const uint4*)(relbf + (size_t)(base3 + rw) * HEADD + cc);
                }
            }
        }
        __syncthreads();

        // ---- score MFMAs ----
        f32x4 accS[2] = {};
        if (w < 2) {
            #pragma unroll
            for (int ct = 0; ct < 2; ++ct) {
                s16x8 kb0 = *(const s16x8*)&K_s[ct * 16 + colA][kg8];
                s16x8 kb1 = *(const s16x8*)&K_s[ct * 16 + colA][kg8 + 32];
                accS[ct] = __builtin_amdgcn_mfma_f32_16x16x32_bf16(qa0, kb0, accS[ct], 0, 0, 0);
                accS[ct] = __builtin_amdgcn_mfma_f32_16x16x32_bf16(qa1, kb1, accS[ct], 0, 0, 0);
            }
        } else {
            const int wr = w - 2;
            s16x8 ka0 = *(const s16x8*)&K_s[wr * 16 + colA][kg8];
            s16x8 ka1 = *(const s16x8*)&K_s[wr * 16 + colA][kg8 + 32];
            #pragma unroll
            for (int ut = 0; ut < 4; ++ut) {
                int urow = ut * 16 + colA;
                unsigned sw0 = ((unsigned)(urow * 128 + kg8 * 2)) ^ (unsigned)((urow & 7) << 4);
                unsigned sw1 = ((unsigned)(urow * 128 + (kg8 + 32) * 2)) ^ (unsigned)((urow & 7) << 4);
                s16x8 rb0 = *(const s16x8*)((char*)R2_s + sw0);
                s16x8 rb1 = *(const s16x8*)((char*)R2_s + sw1);
                f32x4 c2 = {};
                c2 = __builtin_amdgcn_mfma_f32_16x16x32_bf16(qb0, rb0, c2, 0, 0, 0);
                c2 = __builtin_amdgcn_mfma_f32_16x16x32_bf16(qb1, rb1, c2, 0, 0, 0);
                ushort4 p2;
                p2.x = f2bf(c2[0]); p2.y = f2bf(c2[1]); p2.z = f2bf(c2[2]); p2.w = f2bf(c2[3]);
                *(ushort4*)&M2t_s[urow][wr * 16 + g * 4] = p2;
                s16x8 sb0 = *(const s16x8*)((char*)R3_s + sw0);
                s16x8 sb1 = *(const s16x8*)((char*)R3_s + sw1);
                f32x4 c3 = {};
                c3 = __builtin_amdgcn_mfma_f32_16x16x32_bf16(ka0, sb0, c3, 0, 0, 0);
                c3 = __builtin_amdgcn_mfma_f32_16x16x32_bf16(ka1, sb1, c3, 0, 0, 0);
                ushort4 p3;
                p3.x = f2bf(c3[0]); p3.y = f2bf(c3[1]); p3.z = f2bf(c3[2]); p3.w = f2bf(c3[3]);
                *(ushort4*)&M3t_s[urow][wr * 16 + g * 4] = p3;
            }
        }
        __syncthreads();

        // ---- softmax (W0/W1 only; rows orow..orow+15, full 32 cols) ----
        if (w < 2) {
            float sv[2][4];
            #pragma unroll
            for (int ct = 0; ct < 2; ++ct) {
                int col = ct * 16 + colA;
                bool ok = (j0 + col) < S;
                #pragma unroll
                for (int rr = 0; rr < 4; ++rr) {
                    int grow = orow + g * 4 + rr;
                    float s2 = bf2f(M2t_s[col - grow + 31][grow]);
                    float s3 = bf2f(M3t_s[grow - col + 31][col]);
                    float s = accS[ct][rr] + s2 + s3;
                    sv[ct][rr] = ok ? s : -1e30f;
                }
            }
            #pragma unroll
            for (int rr = 0; rr < 4; ++rr) {
                float mm = fmaxf(sv[0][rr], sv[1][rr]);
                mm = fmaxf(mm, __shfl_xor(mm, 1));
                mm = fmaxf(mm, __shfl_xor(mm, 2));
                mm = fmaxf(mm, __shfl_xor(mm, 4));
                mm = fmaxf(mm, __shfl_xor(mm, 8));
                float mnew = fmaxf(m_run[rr], mm);
                float sc = exp2f((m_run[rr] - mnew) * LOG2E);
                m_run[rr] = mnew;
                float p0 = exp2f((sv[0][rr] - mnew) * LOG2E);
                float p1 = exp2f((sv[1][rr] - mnew) * LOG2E);
                P_s[orow + g * 4 + rr][colA]      = f2bf(p0);
                P_s[orow + g * 4 + rr][16 + colA] = f2bf(p1);
                float pp = p0 + p1;
                pp += __shfl_xor(pp, 1);
                pp += __shfl_xor(pp, 2);
                pp += __shfl_xor(pp, 4);
                pp += __shfl_xor(pp, 8);
                l_run[rr] = l_run[rr] * sc + pp;
                if (colA == 0) scale_s[orow + g * 4 + rr] = sc;
            }
        }
        __syncthreads();

        // ---- PV (all waves) ----
        {
            float s0 = scale_s[orow + g * 4 + 0];
            float s1 = scale_s[orow + g * 4 + 1];
            float s2 = scale_s[orow + g * 4 + 2];
            float s3 = scale_s[orow + g * 4 + 3];
            o0[0] *= s0; o0[1] *= s1; o0[2] *= s2; o0[3] *= s3;
            o1[0] *= s0; o1[1] *= s1; o1[2] *= s2; o1[3] *= s3;
            s16x8 pa  = *(const s16x8*)&P_s[orow + colA][kg8];
            s16x8 vb0 = *(const s16x8*)&Vt_s[od + colA][kg8];
            s16x8 vb1 = *(const s16x8*)&Vt_s[od + 16 + colA][kg8];
            o0 = __builtin_amdgcn_mfma_f32_16x16x32_bf16(pa, vb0, o0, 0, 0, 0);
            o1 = __builtin_amdgcn_mfma_f32_16x16x32_bf16(pa, vb1, o1, 0, 0, 0);
        }
        __syncthreads();
    }

    if (w < 2 && colA == 0) {
        #pragma unroll
        for (int rr = 0; rr < 4; ++rr)
            lsum_s[orow + g * 4 + rr] = l_run[rr];
    }
    __syncthreads();
    #pragma unroll
    for (int rr = 0; rr < 4; ++rr) {
        int row = orow + g * 4 + rr;
        float inv = 1.f / lsum_s[row];
        size_t obase = (size_t)(b * SEQ + i0 + row) * HDIM + n * HEADD;
        out[obase + od + colA]      = o0[rr] * inv;
        out[obase + od + 16 + colA] = o1[rr] * inv;
    }
}

extern "C" void kernel_launch(void* const* d_in, const int* in_sizes, int n_in,
                              void* d_out, int out_size, void* d_ws, size_t ws_size,
                              hipStream_t stream) {
    (void)in_sizes; (void)n_in; (void)out_size; (void)ws_size;
    const float* query = (const float*)d_in[0];
    const float* key   = (const float*)d_in[1];
    const float* value = (const float*)d_in[2];
    const float* w_q_w = (const float*)d_in[3];
    const float* w_q_b = (const float*)d_in[4];
    const float* w_v_w = (const float*)d_in[5];
    const float* w_v_b = (const float*)d_in[6];
    const float* w_r_w = (const float*)d_in[7];
    const float* w_r_b = (const float*)d_in[8];
    const float* rrb   = (const float*)d_in[9];
    const float* rwb   = (const float*)d_in[10];
    const int*   seqp  = (const int*)d_in[11];
    float* out = (float*)d_out;

    unsigned short* wsp   = (unsigned short*)d_ws;
    const size_t NTOK = (size_t)BATCH * SEQ * HDIM;   // 2M
    unsigned short* relbf  = wsp;                       // 131072
    unsigned short* kbf    = relbf + (size_t)RELN * HEADD;
    unsigned short* qabf   = kbf + NTOK;
    unsigned short* qbbf   = qabf + NTOK;
    unsigned short* vTbuf  = qbbf + NTOK;
    unsigned short* wtq_hi = vTbuf + NTOK;              // 4 x 262144
    unsigned short* wtq_lo = wtq_hi + (size_t)HDIM * HDIM;
    unsigned short* wtv_hi = wtq_lo + (size_t)HDIM * HDIM;
    unsigned short* wtv_lo = wtv_hi + (size_t)HDIM * HDIM;

    hipLaunchKernelGGL(rel_kernel, dim3(RELN), dim3(256), 0, stream, w_r_w, w_r_b, relbf);
    hipLaunchKernelGGL(wsplit_kernel, dim3(8, 8, 2), dim3(256), 0, stream,
                       w_q_w, w_v_w, wtq_hi, wtq_lo, wtv_hi, wtv_lo);
    hipLaunchKernelGGL(conv_bf16, dim3(2048), dim3(256), 0, stream,
                       key, kbf, (int)NTOK);
    hipLaunchKernelGGL((proj_mfma<0>), dim3(8, 64), dim3(256), 0, stream,
                       query, wtq_hi, wtq_lo, w_q_b, rrb, rwb, qabf, qbbf);
    hipLaunchKernelGGL((proj_mfma<1>), dim3(8, 64), dim3(256), 0, stream,
                       value, wtv_hi, wtv_lo, w_v_b, (const float*)nullptr, (const float*)nullptr,
                       vTbuf, (unsigned short*)nullptr);
    hipLaunchKernelGGL(flash_v3, dim3(SEQ / 32, NHEAD, BATCH), dim3(256), 0, stream,
                       kbf, qabf, qbbf, vTbuf, relbf, seqp, out);
}